// Round 8
// baseline (159.635 us; speedup 1.0000x reference)
//
#include <hip/hip_runtime.h>

// BahdanauAttention_16518444220431 — diagonal-DP recurrence on MI355X (gfx950).
// R18 = R17 (verified, 59.4us chain: pair structure + self-ks + vectorized
// prep) + CROSS-PHASE B-PREFETCH: phase-1's B chunks for ks-slots 4..11 are
// ds_read into regs (bu1[8], +32 regs) right after phase-0's GEMM, before
// pack0 — ~600cyc of cover (pack0 VALU + phase-1 xw/self front). Phase-1
// GEMM runs 10/16 ks from registers. Hazard structure IDENTICAL to R17
// (reads after opening barrier, writes before closing; phase bodies stay
// sequential — NOT R15's fusion, which raced). R17 post-mortem: self-ks is
// the only lever that has moved this kernel (chain 65.4->59.4, MfmaUtil
// 47->53, exactly as predicted); harness floor ~70us, chain is everything.
// Falsified: conflicts (R11), setprio (R11), barrier count (R14), 2-interval
// reg state (R12/R13 spill), fused write (R15 race), block stagger (R16).
// LEDGER: w2c 80 + w1x 8 + zkU/zkD 32 + bu1 32 + afs<=48 + temps ~20 + acc
// 32 AGPR; R17 landed 124 VGPR so +32 should fit. FETCH>10MB = spill ->
// shrink bu1 to 4 next round. LESSONS: launch_bounds (256,2).

typedef __bf16 bf16x8 __attribute__((ext_vector_type(8)));
typedef __bf16 bf16x4 __attribute__((ext_vector_type(4)));
typedef float f32x16 __attribute__((ext_vector_type(16)));
typedef unsigned int uint2v __attribute__((ext_vector_type(2)));

#define MFMA32(a, b, c) __builtin_amdgcn_mfma_f32_32x32x16_bf16(a, b, c, 0, 0, 0)

__device__ __forceinline__ unsigned short f2bf(float f) {
  unsigned int u = __builtin_bit_cast(unsigned int, f);
  u += 0x7fffu + ((u >> 16) & 1u);
  return (unsigned short)(u >> 16);
}

__device__ __forceinline__ unsigned pk2(float a, float b) {
  return (unsigned)f2bf(a) | ((unsigned)f2bf(b) << 16);
}

// ws layout (bf16 elements):
//   [0,65536)        W2 fragments: ((ot*16+ks)*64+lane)*8+j ; o=ot*32+(lane&31), k=ks*16+(lane>>5)*8+j
//   [65536,131072)   W4 fragments, same permutation
//   [131072,135168)  W1-extra frags: lanes<32: j<4 -> W1[o][j], j==4 -> b1[o]+b2[o], else 0
//   [135168,139264)  W3-extra frags: j==4 -> b3[o]+2*b4[o]
__global__ void prep_kernel(const float* __restrict__ W1, const float* __restrict__ b1,
                            const float* __restrict__ W2, const float* __restrict__ b2,
                            const float* __restrict__ W3, const float* __restrict__ b3,
                            const float* __restrict__ W4, const float* __restrict__ b4,
                            unsigned short* __restrict__ ws) {
  int t8 = blockIdx.x * 256 + threadIdx.x;
  if (t8 >= 17408) return;   // 139264 / 8
  int idx = t8 * 8;
  int4 outv;
  if (idx < 131072) {
    const float* W = (idx < 65536) ? W2 : W4;
    int f = (idx & 65535) >> 3;
    int lane = f & 63, slot = f >> 6;
    int ks = slot & 15, ot = slot >> 4;
    int o = ot * 32 + (lane & 31);
    int kbase = ks * 16 + (lane >> 5) * 8;
    const float4* row = (const float4*)(W + o * 256 + kbase);
    float4 v0 = row[0];
    float4 v1 = row[1];
    outv = make_int4((int)pk2(v0.x, v0.y), (int)pk2(v0.z, v0.w),
                     (int)pk2(v1.x, v1.y), (int)pk2(v1.z, v1.w));
  } else {
    int i = idx - 131072;
    bool first = (i < 4096);
    int f = (i & 4095) >> 3;
    int lane = f & 63, ot = f >> 6;
    int o = ot * 32 + (lane & 31);
    outv = make_int4(0, 0, 0, 0);
    if (lane < 32) {
      const float4 wrow = *(const float4*)((first ? W1 : W3) + o * 4);
      float bias = first ? (b1[o] + b2[o]) : (b3[o] + 2.0f * b4[o]);
      outv = make_int4((int)pk2(wrow.x, wrow.y), (int)pk2(wrow.z, wrow.w),
                       (int)pk2(bias, 0.0f), 0);
    }
  }
  *(int4*)(ws + idx) = outv;
}

#define NC 10  // W2 slots cached (0..3 = self ks); slots 10..15 streamed per GEMM

// Load 2 afs slots (physical ks rotated by 4w) into AF[0..1][ot].
#define LOAD_AF(AF, S0) { \
    int ka_ = (4 * w + NC + (S0)) & 15; \
    AF[0][0] = __builtin_bit_cast(bf16x8, w2f[(ot0 * 16 + ka_) * 64 + l]); \
    AF[0][1] = __builtin_bit_cast(bf16x8, w2f[((ot0 + 1) * 16 + ka_) * 64 + l]); \
    int kb_ = (4 * w + NC + (S0) + 1) & 15; \
    AF[1][0] = __builtin_bit_cast(bf16x8, w2f[(ot0 * 16 + kb_) * 64 + l]); \
    AF[1][1] = __builtin_bit_cast(bf16x8, w2f[((ot0 + 1) * 16 + kb_) * 64 + l]); }

// One LDS-sourced K-slice: 1 ds_read_b128 feeds 2 MFMAs. KSR runtime (addr only).
#define GSTEP(RB, KSR, A0, A1) { \
    bf16x8 bu_ = __builtin_bit_cast(bf16x8, (RB)[(2 * (KSR) + khalf) * 32 + lane31]); \
    acc[0] = MFMA32(A0, bu_, acc[0]); \
    acc[1] = MFMA32(A1, bu_, acc[1]); }

// Register-sourced K-slice (B prefetched into BU[I]).
#define GSTEPR(BU, I, A0, A1) { \
    bf16x8 bu_ = __builtin_bit_cast(bf16x8, BU[I]); \
    acc[0] = MFMA32(A0, bu_, acc[0]); \
    acc[1] = MFMA32(A1, bu_, acc[1]); }

// Prefetch one B chunk for ks-slot 4+I of buffer RB into BU[I].
#define PRELOAD1(BU, RB, I) \
    BU[I] = (RB)[(2 * ((4 * w + 4 + (I)) & 15) + khalf) * 32 + lane31];

// Self K-slice from zk registers (zero LDS dependency). S literal 0..3.
#define SELFSTEP(ZK, S) { \
    bf16x8 bu_ = __builtin_bit_cast(bf16x8, ZK[(S) >> 1][(S) & 1]); \
    acc[0] = MFMA32(w2c[0][S], bu_, acc[0]); \
    acc[1] = MFMA32(w2c[1][S], bu_, acc[1]); }

// relu + bf16 pack + permlane32_swap into full-int4 B-frag form -> ZK regs.
// ZK[t2][p] = chunk (ot0+t2)*4 + 2p + khalf, row lane31.
#define PACKZ(ZK) { \
    _Pragma("unroll") for (int t2 = 0; t2 < 2; ++t2) { \
      unsigned lo[4], hi[4]; \
      _Pragma("unroll") for (int q = 0; q < 4; ++q) { \
        bf16x4 h; \
        h.x = (__bf16)fmaxf(acc[t2][4 * q + 0], 0.0f); \
        h.y = (__bf16)fmaxf(acc[t2][4 * q + 1], 0.0f); \
        h.z = (__bf16)fmaxf(acc[t2][4 * q + 2], 0.0f); \
        h.w = (__bf16)fmaxf(acc[t2][4 * q + 3], 0.0f); \
        uint2 u = __builtin_bit_cast(uint2, h); \
        lo[q] = u.x; hi[q] = u.y; \
      } \
      uint2v r0 = __builtin_amdgcn_permlane32_swap(lo[0], lo[1], false, false); \
      uint2v r1 = __builtin_amdgcn_permlane32_swap(hi[0], hi[1], false, false); \
      ZK[t2][0] = make_int4((int)r0.x, (int)r1.x, (int)r0.y, (int)r1.y); \
      uint2v r2 = __builtin_amdgcn_permlane32_swap(lo[2], lo[3], false, false); \
      uint2v r3 = __builtin_amdgcn_permlane32_swap(hi[2], hi[3], false, false); \
      ZK[t2][1] = make_int4((int)r2.x, (int)r3.x, (int)r2.y, (int)r3.y); \
    } }

// Write ZK regs (4 int4) into state buffer WB. Conflict-free 512B runs.
#define WRITEZ(ZK, WB) { \
    _Pragma("unroll") for (int t2 = 0; t2 < 2; ++t2) \
    _Pragma("unroll") for (int p = 0; p < 2; ++p) \
      (WB)[((ot0 + t2) * 4 + 2 * p + khalf) * 32 + lane31] = ZK[t2][p]; }

// xw extra-K term for phase PH at step T.
#define XWSTEP(PH, T) { \
    int widx_ = (PH) == 0 ? (lane31 + (T) - 1) : (lane31 + 17 - (T)); \
    const int4* p_ = (l < 32) ? (xw + widx_) : (&zc); \
    bf16x8 bx_ = __builtin_bit_cast(bf16x8, *p_); \
    acc[0] = MFMA32(w1x[0], bx_, acc[0]); \
    acc[1] = MFMA32(w1x[1], bx_, acc[1]); }

// One fused-SCHEDULE (not fused-compute) pair at step T: phase bodies stay
// sequential (R17 order) but phase-1's B chunks ks 4..11 are prefetched into
// bu1 regs before pack0, giving them ~600cyc of latency cover.
#define INTERVAL_PAIR(T, RA, WA, RB, WB) { \
  int4 bu1[8]; \
  { /* ---- phase 0 (up) ---- */ \
    bf16x8 afA[2][2], afB[2][2], afC[2][2]; \
    LOAD_AF(afA, 0) \
    f32x16 acc[2] = {}; \
    XWSTEP(0, T) \
    __builtin_amdgcn_s_setprio(1); \
    SELFSTEP(zkU, 0) SELFSTEP(zkU, 1) SELFSTEP(zkU, 2) SELFSTEP(zkU, 3) \
    LOAD_AF(afB, 2) \
    GSTEP(RA, (4 * w + 4) & 15, w2c[0][4], w2c[1][4]) \
    GSTEP(RA, (4 * w + 5) & 15, w2c[0][5], w2c[1][5]) \
    GSTEP(RA, (4 * w + 6) & 15, w2c[0][6], w2c[1][6]) \
    GSTEP(RA, (4 * w + 7) & 15, w2c[0][7], w2c[1][7]) \
    GSTEP(RA, (4 * w + 8) & 15, w2c[0][8], w2c[1][8]) \
    GSTEP(RA, (4 * w + 9) & 15, w2c[0][9], w2c[1][9]) \
    GSTEP(RA, (4 * w + 10) & 15, afA[0][0], afA[0][1]) \
    GSTEP(RA, (4 * w + 11) & 15, afA[1][0], afA[1][1]) \
    LOAD_AF(afC, 4) \
    GSTEP(RA, (4 * w + 12) & 15, afB[0][0], afB[0][1]) \
    GSTEP(RA, (4 * w + 13) & 15, afB[1][0], afB[1][1]) \
    GSTEP(RA, (4 * w + 14) & 15, afC[0][0], afC[0][1]) \
    GSTEP(RA, (4 * w + 15) & 15, afC[1][0], afC[1][1]) \
    __builtin_amdgcn_s_setprio(0); \
    PRELOAD1(bu1, RB, 0) PRELOAD1(bu1, RB, 1) PRELOAD1(bu1, RB, 2) \
    PRELOAD1(bu1, RB, 3) PRELOAD1(bu1, RB, 4) PRELOAD1(bu1, RB, 5) \
    PRELOAD1(bu1, RB, 6) PRELOAD1(bu1, RB, 7) \
    PACKZ(zkU) \
    WRITEZ(zkU, WA) \
  } \
  { /* ---- phase 1 (down): ks 4..11 from bu1 regs ---- */ \
    bf16x8 afA[2][2], afB[2][2], afC[2][2]; \
    LOAD_AF(afA, 0) \
    f32x16 acc[2] = {}; \
    XWSTEP(1, T) \
    __builtin_amdgcn_s_setprio(1); \
    SELFSTEP(zkD, 0) SELFSTEP(zkD, 1) SELFSTEP(zkD, 2) SELFSTEP(zkD, 3) \
    LOAD_AF(afB, 2) \
    GSTEPR(bu1, 0, w2c[0][4], w2c[1][4]) \
    GSTEPR(bu1, 1, w2c[0][5], w2c[1][5]) \
    GSTEPR(bu1, 2, w2c[0][6], w2c[1][6]) \
    GSTEPR(bu1, 3, w2c[0][7], w2c[1][7]) \
    GSTEPR(bu1, 4, w2c[0][8], w2c[1][8]) \
    GSTEPR(bu1, 5, w2c[0][9], w2c[1][9]) \
    GSTEPR(bu1, 6, afA[0][0], afA[0][1]) \
    GSTEPR(bu1, 7, afA[1][0], afA[1][1]) \
    LOAD_AF(afC, 4) \
    GSTEP(RB, (4 * w + 12) & 15, afB[0][0], afB[0][1]) \
    GSTEP(RB, (4 * w + 13) & 15, afB[1][0], afB[1][1]) \
    GSTEP(RB, (4 * w + 14) & 15, afC[0][0], afC[0][1]) \
    GSTEP(RB, (4 * w + 15) & 15, afC[1][0], afC[1][1]) \
    __builtin_amdgcn_s_setprio(0); \
    PACKZ(zkD) \
    WRITEZ(zkD, WB) \
  } \
  __syncthreads(); }

// Peel interval (T=1): no GEMM.
#define INTERVAL_P(PH, WB, ZK) { \
  f32x16 acc[2] = {}; \
  XWSTEP(PH, 1) \
  PACKZ(ZK) \
  WRITEZ(ZK, WB) }

__global__ __launch_bounds__(256, 2)
void chain_kernel(const float* __restrict__ x, const unsigned short* __restrict__ ws,
                  float* __restrict__ out) {
  // Per-phase double-buffered state, chunk-major: buf[c*32 + r] = bf16 elems
  // [8c..8c+7] of state row r (32 rows per tile). 4 x 16KB = 64KB.
  __shared__ int4 UA[2][1024];
  __shared__ int4 UB[2][1024];
  __shared__ int4 xw[48];   // [x0,x1,x2,x3,1,0,0,0] bf16 chunks, rows j0-8 .. j0+39
  __shared__ int4 zc;

  const int tid = threadIdx.x;
  const int l = tid & 63;
  const int w = tid >> 6;
  const int lane31 = l & 31;
  const int khalf = l >> 5;
  const int tile = blockIdx.x;
  const int b = tile >> 6;
  const int j0 = (tile & 63) * 32;

  const int4* w2f = (const int4*)ws;
  const int4* w4f = (const int4*)(ws + 65536);
  const int4* w1xg = (const int4*)(ws + 131072);
  const int4* w3xg = (const int4*)(ws + 135168);

  if (tid == 0) zc = make_int4(0, 0, 0, 0);
  if (tid < 48) {
    int j = j0 - 8 + tid;
    int4 c = make_int4(0, 0, 0, 0);
    if (j >= 0 && j < 2048) {
      const float* xb = x + (b * 4) * 2048 + j;
      unsigned short h0 = f2bf(xb[0]);
      unsigned short h1 = f2bf(xb[2048]);
      unsigned short h2 = f2bf(xb[4096]);
      unsigned short h3 = f2bf(xb[6144]);
      c = make_int4((int)(h0 | ((unsigned int)h1 << 16)),
                    (int)(h2 | ((unsigned int)h3 << 16)),
                    0x00003f80, 0);  // chunk[4] = bf16(1.0) multiplies the bias row
    }
    xw[tid] = c;
  }

  const int ot0 = w * 2;
  // Rotated W2 cache: slot i = physical ks (4w+i)&15; slots 0..3 are this
  // wave's SELF ks (matching its own zk chunks) at compile-time indices.
  bf16x8 w2c[2][NC];
  bf16x8 w1x[2];
#pragma unroll
  for (int t2 = 0; t2 < 2; ++t2) {
    w1x[t2] = __builtin_bit_cast(bf16x8, w1xg[(ot0 + t2) * 64 + l]);
#pragma unroll
    for (int i = 0; i < NC; ++i) {
      int ksr = (4 * w + i) & 15;
      w2c[t2][i] = __builtin_bit_cast(bf16x8, w2f[((ot0 + t2) * 16 + ksr) * 64 + l]);
    }
  }
  __syncthreads();

  // zkU/zkD: this wave's packed state (B-frag layout), ks slots [4w,4w+4).
  // Lifetime: packed at pair k, LDS-written same pair, self-consumed pair k+1.
  int4 zkU[2][2], zkD[2][2];

  // ---- pair 0 (T=1): no previous state ----
  INTERVAL_P(0, UA[0], zkU)
  INTERVAL_P(1, UB[0], zkD)
  __syncthreads();

  // ---- pairs 1..7 (T=2..8): one barrier per pair ----
#pragma unroll 1
  for (int k = 1; k < 8; ++k) {
    const int4* ra = UA[(k - 1) & 1];
    int4* wa = UA[k & 1];
    const int4* rb = UB[(k - 1) & 1];
    int4* wb = UB[k & 1];
    INTERVAL_PAIR(k + 1, ra, wa, rb, wb)
  }

  // ---- final: miu^T = relu(W3x + b3 + 2b4 + W4*up(8) + W4*down(8)) ----
  // up(8) in UA[1] + zkU self slots; down(8) in UB[1] + zkD.
  {
    f32x16 acc[2] = {};
    { int widx = lane31 + 8;
      const int4* p_ = (l < 32) ? (xw + widx) : (&zc);
      bf16x8 bx = __builtin_bit_cast(bf16x8, *p_);
      bf16x8 w3x0 = __builtin_bit_cast(bf16x8, w3xg[ot0 * 64 + l]);
      bf16x8 w3x1 = __builtin_bit_cast(bf16x8, w3xg[(ot0 + 1) * 64 + l]);
      acc[0] = MFMA32(w3x0, bx, acc[0]);
      acc[1] = MFMA32(w3x1, bx, acc[1]); }
    __builtin_amdgcn_s_setprio(1);
#pragma unroll 1
    for (int ph = 0; ph < 2; ++ph) {
      const int4* Sp = ph ? UB[1] : UA[1];
      const int4* zz = ph ? &zkD[0][0] : &zkU[0][0];
#pragma unroll
      for (int s = 0; s < 4; ++s) {
        int ksr = 4 * w + s;
        bf16x8 af0 = __builtin_bit_cast(bf16x8, w4f[(ot0 * 16 + ksr) * 64 + l]);
        bf16x8 af1 = __builtin_bit_cast(bf16x8, w4f[((ot0 + 1) * 16 + ksr) * 64 + l]);
        bf16x8 bu = __builtin_bit_cast(bf16x8, zz[s]);
        acc[0] = MFMA32(af0, bu, acc[0]);
        acc[1] = MFMA32(af1, bu, acc[1]);
      }
#pragma unroll
      for (int i = 4; i < 16; ++i) {
        int ksr = (4 * w + i) & 15;
        bf16x8 af0 = __builtin_bit_cast(bf16x8, w4f[(ot0 * 16 + ksr) * 64 + l]);
        bf16x8 af1 = __builtin_bit_cast(bf16x8, w4f[((ot0 + 1) * 16 + ksr) * 64 + l]);
        bf16x8 bu = __builtin_bit_cast(bf16x8, Sp[(2 * ksr + khalf) * 32 + lane31]);
        acc[0] = MFMA32(af0, bu, acc[0]);
        acc[1] = MFMA32(af1, bu, acc[1]);
      }
    }
    __builtin_amdgcn_s_setprio(0);
    int pbase = (b * 2048 + j0 + lane31) * 256;
#pragma unroll
    for (int t2 = 0; t2 < 2; ++t2) {
#pragma unroll
      for (int q = 0; q < 4; ++q) {
        int ob = (ot0 + t2) * 32 + 8 * q + 4 * khalf;
        float4 v;
        v.x = fmaxf(acc[t2][4 * q + 0], 0.0f);
        v.y = fmaxf(acc[t2][4 * q + 1], 0.0f);
        v.z = fmaxf(acc[t2][4 * q + 2], 0.0f);
        v.w = fmaxf(acc[t2][4 * q + 3], 0.0f);
        *(float4*)(out + pbase + ob) = v;
      }
    }
  }
}

extern "C" void kernel_launch(void* const* d_in, const int* in_sizes, int n_in,
                              void* d_out, int out_size, void* d_ws, size_t ws_size,
                              hipStream_t stream) {
  const float* x  = (const float*)d_in[0];
  const float* W1 = (const float*)d_in[1];
  const float* b1 = (const float*)d_in[2];
  const float* W2 = (const float*)d_in[3];
  const float* b2 = (const float*)d_in[4];
  const float* W3 = (const float*)d_in[5];
  const float* b3 = (const float*)d_in[6];
  const float* W4 = (const float*)d_in[7];
  const float* b4 = (const float*)d_in[8];
  unsigned short* ws = (unsigned short*)d_ws;

  prep_kernel<<<68, 256, 0, stream>>>(W1, b1, W2, b2, W3, b3, W4, b4, ws);
  chain_kernel<<<1024, 256, 0, stream>>>(x, ws, (float*)d_out);
}

// Round 9
// 137.866 us; speedup vs baseline: 1.1579x; 1.1579x over previous
//
#include <hip/hip_runtime.h>

// BahdanauAttention_16518444220431 — diagonal-DP recurrence on MI355X (gfx950).
// R19 = R17 EXACT ARITHMETIC (verified 59.4us chain) with the pair loop FULLY
// UNROLLED so all state-buffer indices are COMPILE-TIME (UA[0]->UA[1], then
// UA[1]->UA[0], ...). Mechanism: R17 passed runtime ptrs (UA[(k-1)&1]) so
// alias analysis couldn't prove RB != WA -> phase-1's 12 ds_reads could not
// hoist above phase-0's WRITEZ; R18 forced that motion with bu1[8] (+32
// forced-live regs) and SPILLED (VGPR cap ~128: R12/R13/R18 all spilled at
// +32 over R17's 124). Static indices give the scheduler LEGAL freedom to
// hoist phase-1 reads into phase-0's pack tail at its own pressure-aware
// depth — R18's mechanism, zero forced cost. T/xw indices become literals.
// Falsified: conflicts (R11), setprio (R11), barrier count (R14), forced
// cross-section reg state (R12/R13/R18 spill), fused write (R15 race),
// block stagger (R16). PROVEN: self-ks latency-hiding (R17: 65.4->59.4,
// predicted), vectorized prep, ~70us harness floor (chain is everything).
// LESSONS: launch_bounds (256,2); FETCH>10MB = spill tripwire.

typedef __bf16 bf16x8 __attribute__((ext_vector_type(8)));
typedef __bf16 bf16x4 __attribute__((ext_vector_type(4)));
typedef float f32x16 __attribute__((ext_vector_type(16)));
typedef unsigned int uint2v __attribute__((ext_vector_type(2)));

#define MFMA32(a, b, c) __builtin_amdgcn_mfma_f32_32x32x16_bf16(a, b, c, 0, 0, 0)

__device__ __forceinline__ unsigned short f2bf(float f) {
  unsigned int u = __builtin_bit_cast(unsigned int, f);
  u += 0x7fffu + ((u >> 16) & 1u);
  return (unsigned short)(u >> 16);
}

__device__ __forceinline__ unsigned pk2(float a, float b) {
  return (unsigned)f2bf(a) | ((unsigned)f2bf(b) << 16);
}

// ws layout (bf16 elements):
//   [0,65536)        W2 fragments: ((ot*16+ks)*64+lane)*8+j ; o=ot*32+(lane&31), k=ks*16+(lane>>5)*8+j
//   [65536,131072)   W4 fragments, same permutation
//   [131072,135168)  W1-extra frags: lanes<32: j<4 -> W1[o][j], j==4 -> b1[o]+b2[o], else 0
//   [135168,139264)  W3-extra frags: j==4 -> b3[o]+2*b4[o]
__global__ void prep_kernel(const float* __restrict__ W1, const float* __restrict__ b1,
                            const float* __restrict__ W2, const float* __restrict__ b2,
                            const float* __restrict__ W3, const float* __restrict__ b3,
                            const float* __restrict__ W4, const float* __restrict__ b4,
                            unsigned short* __restrict__ ws) {
  int t8 = blockIdx.x * 256 + threadIdx.x;
  if (t8 >= 17408) return;   // 139264 / 8
  int idx = t8 * 8;
  int4 outv;
  if (idx < 131072) {
    const float* W = (idx < 65536) ? W2 : W4;
    int f = (idx & 65535) >> 3;
    int lane = f & 63, slot = f >> 6;
    int ks = slot & 15, ot = slot >> 4;
    int o = ot * 32 + (lane & 31);
    int kbase = ks * 16 + (lane >> 5) * 8;
    const float4* row = (const float4*)(W + o * 256 + kbase);
    float4 v0 = row[0];
    float4 v1 = row[1];
    outv = make_int4((int)pk2(v0.x, v0.y), (int)pk2(v0.z, v0.w),
                     (int)pk2(v1.x, v1.y), (int)pk2(v1.z, v1.w));
  } else {
    int i = idx - 131072;
    bool first = (i < 4096);
    int f = (i & 4095) >> 3;
    int lane = f & 63, ot = f >> 6;
    int o = ot * 32 + (lane & 31);
    outv = make_int4(0, 0, 0, 0);
    if (lane < 32) {
      const float4 wrow = *(const float4*)((first ? W1 : W3) + o * 4);
      float bias = first ? (b1[o] + b2[o]) : (b3[o] + 2.0f * b4[o]);
      outv = make_int4((int)pk2(wrow.x, wrow.y), (int)pk2(wrow.z, wrow.w),
                       (int)pk2(bias, 0.0f), 0);
    }
  }
  *(int4*)(ws + idx) = outv;
}

#define NC 10  // W2 slots cached (0..3 = self ks); slots 10..15 streamed per GEMM

// Load 2 afs slots (physical ks rotated by 4w) into AF[0..1][ot].
#define LOAD_AF(AF, S0) { \
    int ka_ = (4 * w + NC + (S0)) & 15; \
    AF[0][0] = __builtin_bit_cast(bf16x8, w2f[(ot0 * 16 + ka_) * 64 + l]); \
    AF[0][1] = __builtin_bit_cast(bf16x8, w2f[((ot0 + 1) * 16 + ka_) * 64 + l]); \
    int kb_ = (4 * w + NC + (S0) + 1) & 15; \
    AF[1][0] = __builtin_bit_cast(bf16x8, w2f[(ot0 * 16 + kb_) * 64 + l]); \
    AF[1][1] = __builtin_bit_cast(bf16x8, w2f[((ot0 + 1) * 16 + kb_) * 64 + l]); }

// One LDS-sourced K-slice: 1 ds_read_b128 feeds 2 MFMAs. KSR runtime (addr only).
#define GSTEP(RB, KSR, A0, A1) { \
    bf16x8 bu_ = __builtin_bit_cast(bf16x8, (RB)[(2 * (KSR) + khalf) * 32 + lane31]); \
    acc[0] = MFMA32(A0, bu_, acc[0]); \
    acc[1] = MFMA32(A1, bu_, acc[1]); }

// Self K-slice from zk registers (zero LDS dependency). S literal 0..3.
#define SELFSTEP(ZK, S) { \
    bf16x8 bu_ = __builtin_bit_cast(bf16x8, ZK[(S) >> 1][(S) & 1]); \
    acc[0] = MFMA32(w2c[0][S], bu_, acc[0]); \
    acc[1] = MFMA32(w2c[1][S], bu_, acc[1]); }

// relu + bf16 pack + permlane32_swap into full-int4 B-frag form -> ZK regs.
// ZK[t2][p] = chunk (ot0+t2)*4 + 2p + khalf, row lane31.
#define PACKZ(ZK) { \
    _Pragma("unroll") for (int t2 = 0; t2 < 2; ++t2) { \
      unsigned lo[4], hi[4]; \
      _Pragma("unroll") for (int q = 0; q < 4; ++q) { \
        bf16x4 h; \
        h.x = (__bf16)fmaxf(acc[t2][4 * q + 0], 0.0f); \
        h.y = (__bf16)fmaxf(acc[t2][4 * q + 1], 0.0f); \
        h.z = (__bf16)fmaxf(acc[t2][4 * q + 2], 0.0f); \
        h.w = (__bf16)fmaxf(acc[t2][4 * q + 3], 0.0f); \
        uint2 u = __builtin_bit_cast(uint2, h); \
        lo[q] = u.x; hi[q] = u.y; \
      } \
      uint2v r0 = __builtin_amdgcn_permlane32_swap(lo[0], lo[1], false, false); \
      uint2v r1 = __builtin_amdgcn_permlane32_swap(hi[0], hi[1], false, false); \
      ZK[t2][0] = make_int4((int)r0.x, (int)r1.x, (int)r0.y, (int)r1.y); \
      uint2v r2 = __builtin_amdgcn_permlane32_swap(lo[2], lo[3], false, false); \
      uint2v r3 = __builtin_amdgcn_permlane32_swap(hi[2], hi[3], false, false); \
      ZK[t2][1] = make_int4((int)r2.x, (int)r3.x, (int)r2.y, (int)r3.y); \
    } }

// Write ZK regs (4 int4) into state buffer WB. Conflict-free 512B runs.
#define WRITEZ(ZK, WB) { \
    _Pragma("unroll") for (int t2 = 0; t2 < 2; ++t2) \
    _Pragma("unroll") for (int p = 0; p < 2; ++p) \
      (WB)[((ot0 + t2) * 4 + 2 * p + khalf) * 32 + lane31] = ZK[t2][p]; }

// xw extra-K term for phase PH at step T (both compile-time here).
#define XWSTEP(PH, T) { \
    int widx_ = (PH) == 0 ? (lane31 + (T) - 1) : (lane31 + 17 - (T)); \
    const int4* p_ = (l < 32) ? (xw + widx_) : (&zc); \
    bf16x8 bx_ = __builtin_bit_cast(bf16x8, *p_); \
    acc[0] = MFMA32(w1x[0], bx_, acc[0]); \
    acc[1] = MFMA32(w1x[1], bx_, acc[1]); }

// Full DP interval with GEMM: self ks 0..3 from ZK (state T-1), ks 4..15
// cached/streamed, then ZK := state T (packed) and written to WB.
// RB/WB are COMPILE-TIME array references (R19).
#define INTERVAL_G(PH, T, RB, WB, ZK) { \
  bf16x8 afA[2][2], afB[2][2], afC[2][2]; \
  LOAD_AF(afA, 0) \
  f32x16 acc[2] = {}; \
  XWSTEP(PH, T) \
  __builtin_amdgcn_s_setprio(1); \
  SELFSTEP(ZK, 0) SELFSTEP(ZK, 1) SELFSTEP(ZK, 2) SELFSTEP(ZK, 3) \
  LOAD_AF(afB, 2) \
  GSTEP(RB, (4 * w + 4) & 15, w2c[0][4], w2c[1][4]) \
  GSTEP(RB, (4 * w + 5) & 15, w2c[0][5], w2c[1][5]) \
  GSTEP(RB, (4 * w + 6) & 15, w2c[0][6], w2c[1][6]) \
  GSTEP(RB, (4 * w + 7) & 15, w2c[0][7], w2c[1][7]) \
  GSTEP(RB, (4 * w + 8) & 15, w2c[0][8], w2c[1][8]) \
  GSTEP(RB, (4 * w + 9) & 15, w2c[0][9], w2c[1][9]) \
  GSTEP(RB, (4 * w + 10) & 15, afA[0][0], afA[0][1]) \
  GSTEP(RB, (4 * w + 11) & 15, afA[1][0], afA[1][1]) \
  LOAD_AF(afC, 4) \
  GSTEP(RB, (4 * w + 12) & 15, afB[0][0], afB[0][1]) \
  GSTEP(RB, (4 * w + 13) & 15, afB[1][0], afB[1][1]) \
  GSTEP(RB, (4 * w + 14) & 15, afC[0][0], afC[0][1]) \
  GSTEP(RB, (4 * w + 15) & 15, afC[1][0], afC[1][1]) \
  __builtin_amdgcn_s_setprio(0); \
  PACKZ(ZK) \
  WRITEZ(ZK, WB) }

// One up+down pair at compile-time step T, reading buffer index RI, writing WI.
#define PAIR(T, RI, WI) \
  INTERVAL_G(0, T, UA[RI], UA[WI], zkU) \
  INTERVAL_G(1, T, UB[RI], UB[WI], zkD) \
  __syncthreads();

// Peel interval (T=1): no GEMM.
#define INTERVAL_P(PH, WB, ZK) { \
  f32x16 acc[2] = {}; \
  XWSTEP(PH, 1) \
  PACKZ(ZK) \
  WRITEZ(ZK, WB) }

__global__ __launch_bounds__(256, 2)
void chain_kernel(const float* __restrict__ x, const unsigned short* __restrict__ ws,
                  float* __restrict__ out) {
  // Per-phase double-buffered state, chunk-major: buf[c*32 + r] = bf16 elems
  // [8c..8c+7] of state row r (32 rows per tile). 4 x 16KB = 64KB.
  __shared__ int4 UA[2][1024];
  __shared__ int4 UB[2][1024];
  __shared__ int4 xw[48];   // [x0,x1,x2,x3,1,0,0,0] bf16 chunks, rows j0-8 .. j0+39
  __shared__ int4 zc;

  const int tid = threadIdx.x;
  const int l = tid & 63;
  const int w = tid >> 6;
  const int lane31 = l & 31;
  const int khalf = l >> 5;
  const int tile = blockIdx.x;
  const int b = tile >> 6;
  const int j0 = (tile & 63) * 32;

  const int4* w2f = (const int4*)ws;
  const int4* w4f = (const int4*)(ws + 65536);
  const int4* w1xg = (const int4*)(ws + 131072);
  const int4* w3xg = (const int4*)(ws + 135168);

  if (tid == 0) zc = make_int4(0, 0, 0, 0);
  if (tid < 48) {
    int j = j0 - 8 + tid;
    int4 c = make_int4(0, 0, 0, 0);
    if (j >= 0 && j < 2048) {
      const float* xb = x + (b * 4) * 2048 + j;
      unsigned short h0 = f2bf(xb[0]);
      unsigned short h1 = f2bf(xb[2048]);
      unsigned short h2 = f2bf(xb[4096]);
      unsigned short h3 = f2bf(xb[6144]);
      c = make_int4((int)(h0 | ((unsigned int)h1 << 16)),
                    (int)(h2 | ((unsigned int)h3 << 16)),
                    0x00003f80, 0);  // chunk[4] = bf16(1.0) multiplies the bias row
    }
    xw[tid] = c;
  }

  const int ot0 = w * 2;
  // Rotated W2 cache: slot i = physical ks (4w+i)&15; slots 0..3 are this
  // wave's SELF ks (matching its own zk chunks) at compile-time indices.
  bf16x8 w2c[2][NC];
  bf16x8 w1x[2];
#pragma unroll
  for (int t2 = 0; t2 < 2; ++t2) {
    w1x[t2] = __builtin_bit_cast(bf16x8, w1xg[(ot0 + t2) * 64 + l]);
#pragma unroll
    for (int i = 0; i < NC; ++i) {
      int ksr = (4 * w + i) & 15;
      w2c[t2][i] = __builtin_bit_cast(bf16x8, w2f[((ot0 + t2) * 16 + ksr) * 64 + l]);
    }
  }
  __syncthreads();

  // zkU/zkD: this wave's packed state (B-frag layout), ks slots [4w,4w+4).
  // Lifetime: packed at pair k, LDS-written same pair, self-consumed pair k+1.
  int4 zkU[2][2], zkD[2][2];

  // ---- pair 0 (T=1): no previous state ----
  INTERVAL_P(0, UA[0], zkU)
  INTERVAL_P(1, UB[0], zkD)
  __syncthreads();

  // ---- pairs T=2..8, fully unrolled, compile-time buffer roles ----
  PAIR(2, 0, 1)
  PAIR(3, 1, 0)
  PAIR(4, 0, 1)
  PAIR(5, 1, 0)
  PAIR(6, 0, 1)
  PAIR(7, 1, 0)
  PAIR(8, 0, 1)

  // ---- final: miu^T = relu(W3x + b3 + 2b4 + W4*up(8) + W4*down(8)) ----
  // up(8) in UA[1] + zkU self slots; down(8) in UB[1] + zkD.
  {
    f32x16 acc[2] = {};
    { int widx = lane31 + 8;
      const int4* p_ = (l < 32) ? (xw + widx) : (&zc);
      bf16x8 bx = __builtin_bit_cast(bf16x8, *p_);
      bf16x8 w3x0 = __builtin_bit_cast(bf16x8, w3xg[ot0 * 64 + l]);
      bf16x8 w3x1 = __builtin_bit_cast(bf16x8, w3xg[(ot0 + 1) * 64 + l]);
      acc[0] = MFMA32(w3x0, bx, acc[0]);
      acc[1] = MFMA32(w3x1, bx, acc[1]); }
    __builtin_amdgcn_s_setprio(1);
#pragma unroll 1
    for (int ph = 0; ph < 2; ++ph) {
      const int4* Sp = ph ? UB[1] : UA[1];
      const int4* zz = ph ? &zkD[0][0] : &zkU[0][0];
#pragma unroll
      for (int s = 0; s < 4; ++s) {
        int ksr = 4 * w + s;
        bf16x8 af0 = __builtin_bit_cast(bf16x8, w4f[(ot0 * 16 + ksr) * 64 + l]);
        bf16x8 af1 = __builtin_bit_cast(bf16x8, w4f[((ot0 + 1) * 16 + ksr) * 64 + l]);
        bf16x8 bu = __builtin_bit_cast(bf16x8, zz[s]);
        acc[0] = MFMA32(af0, bu, acc[0]);
        acc[1] = MFMA32(af1, bu, acc[1]);
      }
#pragma unroll
      for (int i = 4; i < 16; ++i) {
        int ksr = (4 * w + i) & 15;
        bf16x8 af0 = __builtin_bit_cast(bf16x8, w4f[(ot0 * 16 + ksr) * 64 + l]);
        bf16x8 af1 = __builtin_bit_cast(bf16x8, w4f[((ot0 + 1) * 16 + ksr) * 64 + l]);
        bf16x8 bu = __builtin_bit_cast(bf16x8, Sp[(2 * ksr + khalf) * 32 + lane31]);
        acc[0] = MFMA32(af0, bu, acc[0]);
        acc[1] = MFMA32(af1, bu, acc[1]);
      }
    }
    __builtin_amdgcn_s_setprio(0);
    int pbase = (b * 2048 + j0 + lane31) * 256;
#pragma unroll
    for (int t2 = 0; t2 < 2; ++t2) {
#pragma unroll
      for (int q = 0; q < 4; ++q) {
        int ob = (ot0 + t2) * 32 + 8 * q + 4 * khalf;
        float4 v;
        v.x = fmaxf(acc[t2][4 * q + 0], 0.0f);
        v.y = fmaxf(acc[t2][4 * q + 1], 0.0f);
        v.z = fmaxf(acc[t2][4 * q + 2], 0.0f);
        v.w = fmaxf(acc[t2][4 * q + 3], 0.0f);
        *(float4*)(out + pbase + ob) = v;
      }
    }
  }
}

extern "C" void kernel_launch(void* const* d_in, const int* in_sizes, int n_in,
                              void* d_out, int out_size, void* d_ws, size_t ws_size,
                              hipStream_t stream) {
  const float* x  = (const float*)d_in[0];
  const float* W1 = (const float*)d_in[1];
  const float* b1 = (const float*)d_in[2];
  const float* W2 = (const float*)d_in[3];
  const float* b2 = (const float*)d_in[4];
  const float* W3 = (const float*)d_in[5];
  const float* b3 = (const float*)d_in[6];
  const float* W4 = (const float*)d_in[7];
  const float* b4 = (const float*)d_in[8];
  unsigned short* ws = (unsigned short*)d_ws;

  prep_kernel<<<68, 256, 0, stream>>>(W1, b1, W2, b2, W3, b3, W4, b4, ws);
  chain_kernel<<<1024, 256, 0, stream>>>(x, ws, (float*)d_out);
}

// Round 10
// 130.989 us; speedup vs baseline: 1.2187x; 1.0525x over previous
//
#include <hip/hip_runtime.h>

// BahdanauAttention_16518444220431 — diagonal-DP recurrence on MI355X (gfx950).
// R20 = R17's pair structure at DOUBLE OCCUPANCY: 512-thread blocks, 8 waves,
// each wave owns ONE 32-output tile (ot=w) -> per-wave state halves (ledger
// ~100 <= 128 cap) -> launch_bounds(512,4) = 2 blocks/CU = 4 waves/SIMD.
// Theory: every round so far ran 2 waves/SIMD; MfmaUtil pinned ~53% with
// lgkm/dep stalls that no intra-wave scheduling cracked (R11/R14/R16/R18/R19
// all neutral-or-worse). TLP is the untested axis: 4 waves/SIMD covers one
// wave's read-warmup/pack with three others. Dense MFMA/SIMD unchanged
// (4x17 = 2x34 per interval). Self-ks survives halved: self ks = {2w,2w+1},
// rotation (2w+i)&15, NC=4 (slots 0,1 self + 2 cached), stream 12 slots in
// 8-reg batches, 3 rotating names. Keep ROLLED loop (R19: full unroll blew
// I$, 59->73us). LEDGER: acc 16 + w2c 32 + w1x 4 + zkU/zkD 16 + afs<=24 +
// temps ~25 = ~117 < 128. Falsified: conflicts (R11), setprio-as-lever
// (R11), barrier count (R14), forced reg prefetch (R12/R13/R18 spill),
// fused write (R15 race), stagger (R16), full unroll (R19 I$). PROVEN:
// self-ks (R17: 65.4->59.4), vectorized prep, ~70us harness floor.
// Tripwire: FETCH>10MB = spill -> fallback NC=2; Occupancy ~33 + chain flat
// -> LDS-pipe co-limit, structure ceiling.

typedef __bf16 bf16x8 __attribute__((ext_vector_type(8)));
typedef __bf16 bf16x4 __attribute__((ext_vector_type(4)));
typedef float f32x16 __attribute__((ext_vector_type(16)));
typedef unsigned int uint2v __attribute__((ext_vector_type(2)));

#define MFMA32(a, b, c) __builtin_amdgcn_mfma_f32_32x32x16_bf16(a, b, c, 0, 0, 0)

__device__ __forceinline__ unsigned short f2bf(float f) {
  unsigned int u = __builtin_bit_cast(unsigned int, f);
  u += 0x7fffu + ((u >> 16) & 1u);
  return (unsigned short)(u >> 16);
}

__device__ __forceinline__ unsigned pk2(float a, float b) {
  return (unsigned)f2bf(a) | ((unsigned)f2bf(b) << 16);
}

// ws layout (bf16 elements):
//   [0,65536)        W2 fragments: ((ot*16+ks)*64+lane)*8+j ; o=ot*32+(lane&31), k=ks*16+(lane>>5)*8+j
//   [65536,131072)   W4 fragments, same permutation
//   [131072,135168)  W1-extra frags: lanes<32: j<4 -> W1[o][j], j==4 -> b1[o]+b2[o], else 0
//   [135168,139264)  W3-extra frags: j==4 -> b3[o]+2*b4[o]
__global__ void prep_kernel(const float* __restrict__ W1, const float* __restrict__ b1,
                            const float* __restrict__ W2, const float* __restrict__ b2,
                            const float* __restrict__ W3, const float* __restrict__ b3,
                            const float* __restrict__ W4, const float* __restrict__ b4,
                            unsigned short* __restrict__ ws) {
  int t8 = blockIdx.x * 256 + threadIdx.x;
  if (t8 >= 17408) return;   // 139264 / 8
  int idx = t8 * 8;
  int4 outv;
  if (idx < 131072) {
    const float* W = (idx < 65536) ? W2 : W4;
    int f = (idx & 65535) >> 3;
    int lane = f & 63, slot = f >> 6;
    int ks = slot & 15, ot = slot >> 4;
    int o = ot * 32 + (lane & 31);
    int kbase = ks * 16 + (lane >> 5) * 8;
    const float4* row = (const float4*)(W + o * 256 + kbase);
    float4 v0 = row[0];
    float4 v1 = row[1];
    outv = make_int4((int)pk2(v0.x, v0.y), (int)pk2(v0.z, v0.w),
                     (int)pk2(v1.x, v1.y), (int)pk2(v1.z, v1.w));
  } else {
    int i = idx - 131072;
    bool first = (i < 4096);
    int f = (i & 4095) >> 3;
    int lane = f & 63, ot = f >> 6;
    int o = ot * 32 + (lane & 31);
    outv = make_int4(0, 0, 0, 0);
    if (lane < 32) {
      const float4 wrow = *(const float4*)((first ? W1 : W3) + o * 4);
      float bias = first ? (b1[o] + b2[o]) : (b3[o] + 2.0f * b4[o]);
      outv = make_int4((int)pk2(wrow.x, wrow.y), (int)pk2(wrow.z, wrow.w),
                       (int)pk2(bias, 0.0f), 0);
    }
  }
  *(int4*)(ws + idx) = outv;
}

// ---- R20 wave model: 512 threads = 8 waves, wave w owns output tile ot=w.
// Self ks = {2w, 2w+1}; w2c slot i = physical ks (2w+i)&15, i<NC=4.
// Streamed slots 4..15 in 2-slot batches (8 regs each), 3 rotating names.

// Load 2 streamed slots (i, i+1) into AF[0..1].
#define LOAD_AF(AF, I) { \
    int ka_ = (2 * w + (I)) & 15; \
    AF[0] = __builtin_bit_cast(bf16x8, w2f[(ot * 16 + ka_) * 64 + l]); \
    int kb_ = (2 * w + (I) + 1) & 15; \
    AF[1] = __builtin_bit_cast(bf16x8, w2f[(ot * 16 + kb_) * 64 + l]); }

// One LDS-sourced K-slice: 1 ds_read_b128 feeds 1 MFMA. KSR runtime (addr only).
#define GSTEP(RB, KSR, A0) { \
    bf16x8 bu_ = __builtin_bit_cast(bf16x8, (RB)[(2 * (KSR) + khalf) * 32 + lane31]); \
    acc = MFMA32(A0, bu_, acc); }

// Self K-slice from zk registers (zero LDS dependency). S literal 0..1.
#define SELFSTEP(ZK, S) { \
    bf16x8 bu_ = __builtin_bit_cast(bf16x8, ZK[S]); \
    acc = MFMA32(w2c[S], bu_, acc); }

// relu + bf16 pack + permlane32_swap into full-int4 B-frag form -> ZK regs.
// ZK[p] = chunk ot*4 + 2p + khalf, row lane31  (self ks = 2w+p).
#define PACKZ(ZK) { \
    unsigned lo[4], hi[4]; \
    _Pragma("unroll") for (int q = 0; q < 4; ++q) { \
      bf16x4 h; \
      h.x = (__bf16)fmaxf(acc[4 * q + 0], 0.0f); \
      h.y = (__bf16)fmaxf(acc[4 * q + 1], 0.0f); \
      h.z = (__bf16)fmaxf(acc[4 * q + 2], 0.0f); \
      h.w = (__bf16)fmaxf(acc[4 * q + 3], 0.0f); \
      uint2 u = __builtin_bit_cast(uint2, h); \
      lo[q] = u.x; hi[q] = u.y; \
    } \
    uint2v r0 = __builtin_amdgcn_permlane32_swap(lo[0], lo[1], false, false); \
    uint2v r1 = __builtin_amdgcn_permlane32_swap(hi[0], hi[1], false, false); \
    ZK[0] = make_int4((int)r0.x, (int)r1.x, (int)r0.y, (int)r1.y); \
    uint2v r2 = __builtin_amdgcn_permlane32_swap(lo[2], lo[3], false, false); \
    uint2v r3 = __builtin_amdgcn_permlane32_swap(hi[2], hi[3], false, false); \
    ZK[1] = make_int4((int)r2.x, (int)r3.x, (int)r2.y, (int)r3.y); }

// Write ZK regs (2 int4) into state buffer WB. Conflict-free 512B runs.
#define WRITEZ(ZK, WB) { \
    (WB)[(ot * 4 + khalf) * 32 + lane31] = ZK[0]; \
    (WB)[(ot * 4 + 2 + khalf) * 32 + lane31] = ZK[1]; }

// xw extra-K term for phase PH at step T.
#define XWSTEP(PH, T) { \
    int widx_ = (PH) == 0 ? (lane31 + (T) - 1) : (lane31 + 17 - (T)); \
    const int4* p_ = (l < 32) ? (xw + widx_) : (&zc); \
    bf16x8 bx_ = __builtin_bit_cast(bf16x8, *p_); \
    acc = MFMA32(w1x, bx_, acc); }

// Full DP interval with GEMM: self ks slots 0,1 from ZK (state T-1), slots
// 2,3 cached, 4..15 streamed; then ZK := state T, written to WB.
#define INTERVAL_G(PH, T, RB, WB, ZK) { \
  bf16x8 afA[2], afB[2], afC[2]; \
  LOAD_AF(afA, 4) \
  f32x16 acc = {}; \
  XWSTEP(PH, T) \
  __builtin_amdgcn_s_setprio(1); \
  SELFSTEP(ZK, 0) SELFSTEP(ZK, 1) \
  LOAD_AF(afB, 6) \
  GSTEP(RB, (2 * w + 2) & 15, w2c[2]) \
  GSTEP(RB, (2 * w + 3) & 15, w2c[3]) \
  LOAD_AF(afC, 8) \
  GSTEP(RB, (2 * w + 4) & 15, afA[0]) \
  GSTEP(RB, (2 * w + 5) & 15, afA[1]) \
  LOAD_AF(afA, 10) \
  GSTEP(RB, (2 * w + 6) & 15, afB[0]) \
  GSTEP(RB, (2 * w + 7) & 15, afB[1]) \
  LOAD_AF(afB, 12) \
  GSTEP(RB, (2 * w + 8) & 15, afC[0]) \
  GSTEP(RB, (2 * w + 9) & 15, afC[1]) \
  LOAD_AF(afC, 14) \
  GSTEP(RB, (2 * w + 10) & 15, afA[0]) \
  GSTEP(RB, (2 * w + 11) & 15, afA[1]) \
  GSTEP(RB, (2 * w + 12) & 15, afB[0]) \
  GSTEP(RB, (2 * w + 13) & 15, afB[1]) \
  GSTEP(RB, (2 * w + 14) & 15, afC[0]) \
  GSTEP(RB, (2 * w + 15) & 15, afC[1]) \
  __builtin_amdgcn_s_setprio(0); \
  PACKZ(ZK) \
  WRITEZ(ZK, WB) }

// Peel interval (T=1): no GEMM.
#define INTERVAL_P(PH, WB, ZK) { \
  f32x16 acc = {}; \
  XWSTEP(PH, 1) \
  PACKZ(ZK) \
  WRITEZ(ZK, WB) }

__global__ __launch_bounds__(512, 4)
void chain_kernel(const float* __restrict__ x, const unsigned short* __restrict__ ws,
                  float* __restrict__ out) {
  // Per-phase double-buffered state, chunk-major: buf[c*32 + r] = bf16 elems
  // [8c..8c+7] of state row r (32 rows per tile). 4 x 16KB = 64KB.
  __shared__ int4 UA[2][1024];
  __shared__ int4 UB[2][1024];
  __shared__ int4 xw[48];   // [x0,x1,x2,x3,1,0,0,0] bf16 chunks, rows j0-8 .. j0+39
  __shared__ int4 zc;

  const int tid = threadIdx.x;
  const int l = tid & 63;
  const int w = tid >> 6;        // 8 waves
  const int ot = w;              // one 32-output tile per wave
  const int lane31 = l & 31;
  const int khalf = l >> 5;
  const int tile = blockIdx.x;
  const int b = tile >> 6;
  const int j0 = (tile & 63) * 32;

  const int4* w2f = (const int4*)ws;
  const int4* w4f = (const int4*)(ws + 65536);
  const int4* w1xg = (const int4*)(ws + 131072);
  const int4* w3xg = (const int4*)(ws + 135168);

  if (tid == 0) zc = make_int4(0, 0, 0, 0);
  if (tid < 48) {
    int j = j0 - 8 + tid;
    int4 c = make_int4(0, 0, 0, 0);
    if (j >= 0 && j < 2048) {
      const float* xb = x + (b * 4) * 2048 + j;
      unsigned short h0 = f2bf(xb[0]);
      unsigned short h1 = f2bf(xb[2048]);
      unsigned short h2 = f2bf(xb[4096]);
      unsigned short h3 = f2bf(xb[6144]);
      c = make_int4((int)(h0 | ((unsigned int)h1 << 16)),
                    (int)(h2 | ((unsigned int)h3 << 16)),
                    0x00003f80, 0);  // chunk[4] = bf16(1.0) multiplies the bias row
    }
    xw[tid] = c;
  }

  // Rotated W2 cache: slot i = physical ks (2w+i)&15; slots 0,1 = SELF ks.
  bf16x8 w2c[4];
  bf16x8 w1x;
  w1x = __builtin_bit_cast(bf16x8, w1xg[ot * 64 + l]);
#pragma unroll
  for (int i = 0; i < 4; ++i) {
    int ksr = (2 * w + i) & 15;
    w2c[i] = __builtin_bit_cast(bf16x8, w2f[(ot * 16 + ksr) * 64 + l]);
  }
  __syncthreads();

  // zkU/zkD: this wave's packed state (B-frag layout), ks slots {2w, 2w+1}.
  // Lifetime: packed at pair k, LDS-written same pair, self-consumed pair k+1.
  int4 zkU[2], zkD[2];

  // ---- pair 0 (T=1): no previous state ----
  INTERVAL_P(0, UA[0], zkU)
  INTERVAL_P(1, UB[0], zkD)
  __syncthreads();

  // ---- pairs 1..7 (T=2..8): rolled loop (R19: unroll hurts I$) ----
#pragma unroll 1
  for (int k = 1; k < 8; ++k) {
    const int4* ra = UA[(k - 1) & 1];
    int4* wa = UA[k & 1];
    const int4* rb = UB[(k - 1) & 1];
    int4* wb = UB[k & 1];
    const int T = k + 1;
    INTERVAL_G(0, T, ra, wa, zkU)
    INTERVAL_G(1, T, rb, wb, zkD)
    __syncthreads();
  }

  // ---- final: miu^T = relu(W3x + b3 + 2b4 + W4*up(8) + W4*down(8)) ----
  // up(8) in UA[1] + zkU self slots; down(8) in UB[1] + zkD.
  {
    f32x16 acc = {};
    { int widx = lane31 + 8;
      const int4* p_ = (l < 32) ? (xw + widx) : (&zc);
      bf16x8 bx = __builtin_bit_cast(bf16x8, *p_);
      bf16x8 w3x = __builtin_bit_cast(bf16x8, w3xg[ot * 64 + l]);
      acc = MFMA32(w3x, bx, acc); }
    __builtin_amdgcn_s_setprio(1);
#pragma unroll 1
    for (int ph = 0; ph < 2; ++ph) {
      const int4* Sp = ph ? UB[1] : UA[1];
      const int4* zz = ph ? zkD : zkU;
#pragma unroll
      for (int s = 0; s < 2; ++s) {
        int ksr = 2 * w + s;
        bf16x8 af = __builtin_bit_cast(bf16x8, w4f[(ot * 16 + ksr) * 64 + l]);
        bf16x8 bu = __builtin_bit_cast(bf16x8, zz[s]);
        acc = MFMA32(af, bu, acc);
      }
#pragma unroll
      for (int i = 2; i < 16; ++i) {
        int ksr = (2 * w + i) & 15;
        bf16x8 af = __builtin_bit_cast(bf16x8, w4f[(ot * 16 + ksr) * 64 + l]);
        bf16x8 bu = __builtin_bit_cast(bf16x8, Sp[(2 * ksr + khalf) * 32 + lane31]);
        acc = MFMA32(af, bu, acc);
      }
    }
    __builtin_amdgcn_s_setprio(0);
    int pbase = (b * 2048 + j0 + lane31) * 256;
#pragma unroll
    for (int q = 0; q < 4; ++q) {
      int ob = ot * 32 + 8 * q + 4 * khalf;
      float4 v;
      v.x = fmaxf(acc[4 * q + 0], 0.0f);
      v.y = fmaxf(acc[4 * q + 1], 0.0f);
      v.z = fmaxf(acc[4 * q + 2], 0.0f);
      v.w = fmaxf(acc[4 * q + 3], 0.0f);
      *(float4*)(out + pbase + ob) = v;
    }
  }
}

extern "C" void kernel_launch(void* const* d_in, const int* in_sizes, int n_in,
                              void* d_out, int out_size, void* d_ws, size_t ws_size,
                              hipStream_t stream) {
  const float* x  = (const float*)d_in[0];
  const float* W1 = (const float*)d_in[1];
  const float* b1 = (const float*)d_in[2];
  const float* W2 = (const float*)d_in[3];
  const float* b2 = (const float*)d_in[4];
  const float* W3 = (const float*)d_in[5];
  const float* b3 = (const float*)d_in[6];
  const float* W4 = (const float*)d_in[7];
  const float* b4 = (const float*)d_in[8];
  unsigned short* ws = (unsigned short*)d_ws;

  prep_kernel<<<68, 256, 0, stream>>>(W1, b1, W2, b2, W3, b3, W4, b4, ws);
  chain_kernel<<<1024, 512, 0, stream>>>(x, ws, (float*)d_out);
}